// Round 5
// baseline (328.205 us; speedup 1.0000x reference)
//
#include <hip/hip_runtime.h>
#include <hip/hip_bf16.h>

// GCN v15 — v14 base (proven 298 us) + global-atomic degree + gather tail-split.
//   r14 post-mortem: dual-edge gather CONFIRMED (59.5->50.3 us, 3.46 TB/s =
//   92% of the 3.75 TB/s random-row ceiling; FETCH unchanged as predicted).
//   New #1 is k_h (52.8 us): 8x row re-read + 25.6 MB part write + 25.6 MB
//   part re-read in k_ds1, all latency-bound at 5% VALU / 8% HBM, just to
//   build a 400 KB degree histogram. v15: deg[n] u32 via direct global
//   atomicAdd (1.6M uniform-random updates, no hotspot; memset via
//   hipMemsetAsync), col coarse-hist unchanged; k_ds1 deg-read is 400 KB.
//   deg aliases bufA (consumed in d2 before k_fl writes g1 in d4).
//   Gather: clamp logic hoisted out of full 16-edge chunks (VALU trim).

#define FDIM 64
#define NB 256
#define NDEG 512
#define BW 512
#define MAXP 1024
#define GPLIN 1024

typedef __hip_bfloat16 bf16;
typedef short v8s __attribute__((ext_vector_type(8)));
typedef float v4f __attribute__((ext_vector_type(4)));

static __device__ __forceinline__ float ulo2f(unsigned u) {
    union { unsigned x; float f; } v; v.x = u << 16; return v.f;
}
static __device__ __forceinline__ float uhi2f(unsigned u) {
    union { unsigned x; float f; } v; v.x = u & 0xFFFF0000u; return v.f;
}
static __device__ __forceinline__ unsigned f2bu(float f) {
    bf16 b = __float2bfloat16(f);
    return (unsigned)(*(unsigned short*)&b);
}

// --- dispatch 1: col coarse histogram (b<NB) ∥ global-atomic deg (b>=NB) ---
__global__ void k_h(const int* __restrict__ row, const int* __restrict__ col,
                    unsigned* __restrict__ deg, int* __restrict__ M,
                    int E, int n, int P, int CH) {
    __shared__ int h[MAXP];
    int t = threadIdx.x, b = blockIdx.x;
    if (b < NB) {
        for (int i = t; i < P; i += 256) h[i] = 0;
        __syncthreads();
        int s = b * CH, e = min(s + CH, E);
        for (int i = s + t; i < e; i += 256)
            atomicAdd(&h[col[i] >> 9], 1);
        __syncthreads();
        for (int p = t; p < P; p += 256) M[p * NB + b] = h[p];
    } else {
        int db = b - NB;
        for (int i = db * 256 + t; i < E; i += NDEG * 256)
            atomicAdd(&deg[row[i]], 1u);
    }
}

// --- dispatch 2: dis = rsqrt(deg+1) ∥ scan pass 1 ---
__global__ void k_ds1(const unsigned* __restrict__ deg, float* __restrict__ dis,
                      int* __restrict__ M, int* __restrict__ bsum,
                      int n, int ndis, int P) {
    __shared__ int sc[256];
    int t = threadIdx.x, b = blockIdx.x;
    if (b < ndis) {
        int i = b * 256 + t;
        if (i < n) dis[i] = rsqrtf((float)deg[i] + 1.0f);
    } else {
        int sb = b - ndis;
        int i = sb * 256 + t;
        int v = M[i];
        sc[t] = v;
        __syncthreads();
        for (int d = 1; d < 256; d <<= 1) {
            int u = (t >= d) ? sc[t - d] : 0;
            __syncthreads(); sc[t] += u; __syncthreads();
        }
        M[i] = sc[t] - v;
        if (t == 255) bsum[sb] = sc[255];
    }
}

// --- dispatch 3: coarse scatter (inline bsum scan) ---
__global__ void k_csc(const int* __restrict__ row, const int* __restrict__ col,
                      const int* __restrict__ M, const int* __restrict__ bsum,
                      int* __restrict__ s4, int E, int CH, int P) {
    __shared__ int sc[256];
    __shared__ int bs[256];
    __shared__ int cur[MAXP];
    int t = threadIdx.x, b = blockIdx.x;
    int v = (t < P) ? bsum[t] : 0;
    sc[t] = v;
    __syncthreads();
    for (int d = 1; d < 256; d <<= 1) {
        int u = (t >= d) ? sc[t - d] : 0;
        __syncthreads(); sc[t] += u; __syncthreads();
    }
    bs[t] = sc[t] - v;
    __syncthreads();
    for (int p = t; p < P; p += 256) cur[p] = bs[p] + M[p * NB + b];
    __syncthreads();
    int s = b * CH, e = min(s + CH, E);
    for (int i = s + t; i < e; i += 256) {
        int r = row[i], c = col[i];
        int pos = atomicAdd(&cur[c >> 9], 1);
        s4[pos] = (r << 9) | (c & 511);
    }
}

// --- dispatch 4: fine sort (blocks < P) ∥ k_linc (blocks >= P) ---
__global__ __launch_bounds__(256, 4)
void k_fl(const int* __restrict__ s4, const int* __restrict__ M,
          const int* __restrict__ bsum, int* __restrict__ rows4,
          int* __restrict__ off,
          const float* __restrict__ x, const float* __restrict__ feat,
          const float* __restrict__ W, const float* __restrict__ bvec,
          const float* __restrict__ dis, bf16* __restrict__ g1,
          int n, int E, int P) {
    __shared__ int sc[256];
    __shared__ int bs[256];
    __shared__ int hist[BW];
    __shared__ int loff[BW];
    __shared__ int tmp[256];
    __shared__ float sIn[4][FDIM];
    int t = threadIdx.x, b = blockIdx.x;
    if (b < P) {
        int v = (t < P) ? bsum[t] : 0;
        sc[t] = v;
        __syncthreads();
        for (int d = 1; d < 256; d <<= 1) {
            int u = (t >= d) ? sc[t - d] : 0;
            __syncthreads(); sc[t] += u; __syncthreads();
        }
        bs[t] = sc[t] - v;
        __syncthreads();
        int gs = bs[b];
        int ge = gs + bsum[b];
        int c0 = b << 9;
        int lim = n - c0; if (lim > BW) lim = BW;
        hist[2 * t] = 0; hist[2 * t + 1] = 0;
        __syncthreads();
        for (int i = gs + t; i < ge; i += 256)
            atomicAdd(&hist[s4[i] & 511], 1);
        __syncthreads();
        int s0 = hist[2 * t], s1v = hist[2 * t + 1];
        int ps = s0 + s1v;
        tmp[t] = ps;
        __syncthreads();
        for (int d = 1; d < 256; d <<= 1) {
            int u = (t >= d) ? tmp[t - d] : 0;
            __syncthreads(); tmp[t] += u; __syncthreads();
        }
        int ex = tmp[t] - ps;
        loff[2 * t] = ex;
        loff[2 * t + 1] = ex + s0;
        __syncthreads();
        for (int i = t; i < lim; i += 256) off[c0 + i] = gs + loff[i];
        if (b == P - 1 && t == 0) off[n] = E;
        __syncthreads();
        for (int i = gs + t; i < ge; i += 256) {
            int v2 = s4[i];
            int pos = gs + atomicAdd(&loff[v2 & 511], 1);
            rows4[pos] = v2 >> 9;
        }
    } else {                                  // k_linc (r9 proven form)
        int local = t >> 6, j = t & 63;
        float Wreg[FDIM];
        #pragma unroll
        for (int k = 0; k < FDIM; ++k) Wreg[k] = W[k * FDIM + j];
        float bj = bvec[j];
        int gw = (b - P) * 4 + local;
        int nwl = GPLIN * 4;
        for (int w = gw; w < n; w += nwl) {
            sIn[local][j] = (j < 32) ? x[(size_t)w * 32 + j]
                                     : feat[(size_t)w * 32 + (j - 32)];
            __threadfence_block();
            float o = bj;
            #pragma unroll
            for (int k4 = 0; k4 < 16; ++k4) {
                float4 h4 = *(const float4*)&sIn[local][k4 * 4];
                o = fmaf(h4.x, Wreg[4 * k4 + 0], o);
                o = fmaf(h4.y, Wreg[4 * k4 + 1], o);
                o = fmaf(h4.z, Wreg[4 * k4 + 2], o);
                o = fmaf(h4.w, Wreg[4 * k4 + 3], o);
            }
            g1[(size_t)w * FDIM + j] = __float2bfloat16(dis[w] * o);
            __threadfence_block();
        }
    }
}

// --- dual-edge gather: a[w][j] = relu(dis[w]*(g[w][j]+Σ g[r][j])), bf16 out.
// Wave = 1 node; half-wave h carries edge-slot parity, ushort2 per lane =
// 256 B (2 rows) per instruction; 8-deep unroll. v15: full 16-edge chunks
// run without clamp/select VALU; single masked tail chunk.
__global__ __launch_bounds__(256, 8)
void k_gather(const int* __restrict__ rows4, const int* __restrict__ off,
              const float* __restrict__ dis, const bf16* __restrict__ g,
              bf16* __restrict__ a, int n) {
    int t = blockIdx.x * blockDim.x + threadIdx.x;
    int w = t >> 6;
    if (w >= n) return;
    int lane = threadIdx.x & 63;
    int h = lane >> 5;          // edge-slot parity
    int j2 = lane & 31;         // feature pair index
    const unsigned* g32 = (const unsigned*)g;   // one row = 32 uints
    float acc0 = 0.0f, acc1 = 0.0f;
    int s = off[w], e = off[w + 1];
    int k = s;
    for (; k + 16 <= e; k += 16) {
        #pragma unroll
        for (int i = 0; i < 8; ++i) {
            int r = rows4[k + 2 * i + h];
            unsigned u = g32[(size_t)r * 32 + j2];
            acc0 += ulo2f(u);
            acc1 += uhi2f(u);
        }
    }
    if (k < e) {
        #pragma unroll
        for (int i = 0; i < 8; ++i) {
            int idx = k + 2 * i + h;
            int r = rows4[min(idx, e - 1)];
            unsigned u = g32[(size_t)r * 32 + j2];
            float wg = (idx < e) ? 1.0f : 0.0f;
            acc0 = fmaf(wg, ulo2f(u), acc0);
            acc1 = fmaf(wg, uhi2f(u), acc1);
        }
    }
    acc0 += __shfl_xor(acc0, 32, 64);
    acc1 += __shfl_xor(acc1, 32, 64);
    if (h == 0) {
        unsigned su = g32[(size_t)w * 32 + j2];    // self loop
        float dv = dis[w];
        float v0 = fmaxf(dv * (acc0 + ulo2f(su)), 0.0f);
        float v1 = fmaxf(dv * (acc1 + uhi2f(su)), 0.0f);
        ((unsigned*)a)[(size_t)w * 32 + j2] = f2bu(v0) | (f2bu(v1) << 16);
    }
}

// --- MFMA matvec: o = A@W + b ; FINAL ? relu(o) f32 : bf16(dis*o) ---
// Layouts (guide-verified): A-frag A[m=lane&15][k=quad*8+j];
// B-frag B[k=quad*8+j][n=lane&15]; C/D: n=lane&15, m=quad*4+reg.
template <bool FINAL>
__global__ __launch_bounds__(256, 4)
void k_mat(const bf16* __restrict__ A, const float* __restrict__ W,
           const float* __restrict__ bvec, const float* __restrict__ dis,
           void* __restrict__ outp, int n) {
    __shared__ __align__(16) bf16 sWt[FDIM * FDIM];   // Wt[n][k] (transposed)
    int t = threadIdx.x;
    for (int idx = t; idx < FDIM * FDIM; idx += 256) {
        int kk = idx >> 6, nn = idx & 63;
        sWt[nn * FDIM + kk] = __float2bfloat16(W[idx]);
    }
    __syncthreads();
    int wave = t >> 6, lane = t & 63;
    int quad = lane >> 4, l15 = lane & 15;
    v8s bfr[4][2];
    #pragma unroll
    for (int nt = 0; nt < 4; ++nt) {
        #pragma unroll
        for (int kf = 0; kf < 2; ++kf)
            bfr[nt][kf] = *(const v8s*)&sWt[(nt * 16 + l15) * FDIM + kf * 32 + quad * 8];
    }
    float bj[4];
    #pragma unroll
    for (int nt = 0; nt < 4; ++nt) bj[nt] = bvec[nt * 16 + l15];

    int ntiles = (n + 15) >> 4;
    int step = gridDim.x * 4;
    for (int tile = blockIdx.x * 4 + wave; tile < ntiles; tile += step) {
        int m0 = tile << 4;
        int mA = m0 + l15; if (mA >= n) mA = n - 1;
        v8s af0 = *(const v8s*)&A[(size_t)mA * FDIM + quad * 8];
        v8s af1 = *(const v8s*)&A[(size_t)mA * FDIM + 32 + quad * 8];
        v4f acc[4];
        #pragma unroll
        for (int nt = 0; nt < 4; ++nt) {
            acc[nt] = (v4f){0.f, 0.f, 0.f, 0.f};
            acc[nt] = __builtin_amdgcn_mfma_f32_16x16x32_bf16(af0, bfr[nt][0], acc[nt], 0, 0, 0);
            acc[nt] = __builtin_amdgcn_mfma_f32_16x16x32_bf16(af1, bfr[nt][1], acc[nt], 0, 0, 0);
        }
        #pragma unroll
        for (int r = 0; r < 4; ++r) {
            int node = m0 + quad * 4 + r;
            if (node >= n) continue;
            float dv = FINAL ? 0.0f : dis[node];
            #pragma unroll
            for (int nt = 0; nt < 4; ++nt) {
                int j = nt * 16 + l15;
                float o = acc[nt][r] + bj[nt];
                if (FINAL) ((float*)outp)[(size_t)node * FDIM + j] = fmaxf(o, 0.0f);
                else ((bf16*)outp)[(size_t)node * FDIM + j] = __float2bfloat16(dv * o);
            }
        }
    }
}

extern "C" void kernel_launch(void* const* d_in, const int* in_sizes, int n_in,
                              void* d_out, int out_size, void* d_ws, size_t ws_size,
                              hipStream_t stream) {
    const float* x    = (const float*)d_in[0];
    const float* feat = (const float*)d_in[1];
    const int*   ei   = (const int*)d_in[2];
    const float* W1   = (const float*)d_in[3];
    const float* b1   = (const float*)d_in[4];
    const float* W2   = (const float*)d_in[5];
    const float* b2   = (const float*)d_in[6];
    const float* Wfc  = (const float*)d_in[7];
    const float* bfc  = (const float*)d_in[8];
    float* out = (float*)d_out;

    const int n = in_sizes[0] / 32;   // 100000
    const int E = in_sizes[2] / 2;    // 1600000
    const int* row = ei;
    const int* col = ei + E;

    const int P  = (n + BW - 1) / BW;            // 196
    const int CH = (E + NB - 1) / NB;            // 6250
    const int total = P * NB;                    // 50176
    const int ndis = (n + 255) / 256;            // 391

    // ws: off[n+1] | dis[n] | M[total] | bsum[256] | s4[E] | rows4[E]
    //     | (16B-aligned) bufA(bf16 64n) | bufB(bf16 64n)
    // deg (u32[n] = 400 KB) aliases bufA (consumed in k_ds1 before k_fl
    // writes g1 into bufA).
    int*   off  = (int*)d_ws;
    float* dis  = (float*)(off + (size_t)n + 1);
    int*   M    = (int*)(dis + n);
    int*   bsum = M + (size_t)total;
    int*   s4    = bsum + 256;
    int*   rows4 = s4 + E;
    size_t co = (size_t)(rows4 + E - (int*)d_ws);
    co = (co + 3) & ~(size_t)3;                  // 16B align for v8s loads
    bf16*  bufA  = (bf16*)((int*)d_ws + co);
    bf16*  bufB  = bufA + (size_t)n * FDIM;
    unsigned* deg = (unsigned*)bufA;

    const int B = 256;

    hipMemsetAsync(deg, 0, (size_t)n * sizeof(unsigned), stream);
    k_h<<<NB + NDEG, B, 0, stream>>>(row, col, deg, M, E, n, P, CH);
    k_ds1<<<ndis + P, B, 0, stream>>>(deg, dis, M, bsum, n, ndis, P);
    k_csc<<<NB, B, 0, stream>>>(row, col, M, bsum, s4, E, CH, P);
    k_fl<<<P + GPLIN, B, 0, stream>>>(s4, M, bsum, rows4, off,
                                      x, feat, W1, b1, dis, bufA, n, E, P);
    // layer 2: gather(g1)->a1 ; mat: g2 = bf16(dis*(a1@W2+b2))
    k_gather<<<(n + 3) / 4, B, 0, stream>>>(rows4, off, dis, bufA, bufB, n);
    k_mat<false><<<512, B, 0, stream>>>(bufB, W2, b2, dis, bufA, n);
    // fc: gather(g2)->a2 ; out = relu(a2@Wfc+bfc)
    k_gather<<<(n + 3) / 4, B, 0, stream>>>(rows4, off, dis, bufA, bufB, n);
    k_mat<true><<<512, B, 0, stream>>>(bufB, Wfc, bfc, dis, out, n);
}

// Round 6
// 287.188 us; speedup vs baseline: 1.1428x; 1.1428x over previous
//
#include <hip/hip_runtime.h>
#include <hip/hip_bf16.h>

// GCN v16 — v14 base (proven 298 us) + u8-packed LDS degree histogram.
//   r15 post-mortem: global-atomic deg REFUTED — device-scope atomicAdd is
//   a write-through RMW past L2 (WRITE 51.5 MB = 1.6M x 32B, 735 GB/s
//   random-write wall, k_h 70.7 us). Per-XCD L2 non-coherence forces
//   memory-side atomics; never histogram via global atomics here.
//   v16: back to two-stage LDS partials, but u8-packed (max deg ~45 << 255):
//   NPART=4, psize=25000 -> 25 KB LDS (2 blocks/CU vs v12's 1), row re-read
//   4x (25.6 MB, LLC-resident) vs v12's 8x, part array 6.4 MB vs 25.6 MB.
//   k_ds1 reduces 64 u8 partials via packed-u32 reads, 4 nodes/thread.
//   k_gather reverted to v14's exact proven form (50.3 us measured).

#define FDIM 64
#define NPART 4
#define GPB 64
#define NB 256
#define BW 512
#define MAXP 1024
#define GPLIN 1024

typedef __hip_bfloat16 bf16;
typedef short v8s __attribute__((ext_vector_type(8)));
typedef float v4f __attribute__((ext_vector_type(4)));

static __device__ __forceinline__ float ulo2f(unsigned u) {
    union { unsigned x; float f; } v; v.x = u << 16; return v.f;
}
static __device__ __forceinline__ float uhi2f(unsigned u) {
    union { unsigned x; float f; } v; v.x = u & 0xFFFF0000u; return v.f;
}
static __device__ __forceinline__ unsigned f2bu(float f) {
    bf16 b = __float2bfloat16(f);
    return (unsigned)(*(unsigned short*)&b);
}

// --- dispatch 1: deg u8-packed partial histograms (b<NPART*GPB) ∥
//                 coarse col histogram (b>=NPART*GPB) ---
// sm: 6250 u32 = 25000 u8 counters (psize nodes) for deg blocks;
//     re-cast as int[MAXP] for col-hist blocks (4 KB <= 25 KB).
__global__ void k_h(const int* __restrict__ row, const int* __restrict__ col,
                    unsigned* __restrict__ part, int* __restrict__ M,
                    int E, int n, int psize, int psize4, int P, int CH) {
    __shared__ unsigned sm[6256];
    int t = threadIdx.x, b = blockIdx.x;
    if (b < NPART * GPB) {
        int p = b >> 6, g = b & 63;
        int base = p * psize;
        int lim = n - base; if (lim > psize) lim = psize;
        int lim4 = (lim + 3) >> 2;
        for (int i = t; i < lim4; i += 256) sm[i] = 0u;
        __syncthreads();
        #pragma unroll 4
        for (int e = g * 256 + t; e < E; e += GPB * 256) {
            int r = row[e] - base;
            if ((unsigned)r < (unsigned)lim)
                atomicAdd(&sm[r >> 2], 1u << ((r & 3) * 8));
        }
        __syncthreads();
        unsigned* dst = part + ((size_t)p * GPB + g) * psize4;
        for (int i = t; i < lim4; i += 256) dst[i] = sm[i];
    } else {
        int cb = b - NPART * GPB;
        int* h = (int*)sm;
        for (int i = t; i < P; i += 256) h[i] = 0;
        __syncthreads();
        int s = cb * CH, e = min(s + CH, E);
        for (int i = s + t; i < e; i += 256)
            atomicAdd(&h[col[i] >> 9], 1);
        __syncthreads();
        for (int p = t; p < P; p += 256) M[p * NB + cb] = h[p];
    }
}

// --- dispatch 2: dis from u8 partials (4 nodes/thread) ∥ scan pass 1 ---
__global__ void k_ds1(const unsigned* __restrict__ part, float* __restrict__ dis,
                      int* __restrict__ M, int* __restrict__ bsum,
                      int n, int psize4, int ndis4, int P) {
    __shared__ int sc[256];
    int t = threadIdx.x, b = blockIdx.x;
    if (b < ndis4) {
        int i4 = b * 256 + t;
        int i = i4 * 4;
        if (i >= n) return;
        int p = i4 / psize4, loc = i4 - p * psize4;
        const unsigned* src = part + (size_t)p * GPB * psize4 + loc;
        unsigned s0 = 0, s1 = 0, s2 = 0, s3 = 0;
        #pragma unroll 8
        for (int g = 0; g < GPB; ++g) {
            unsigned u = src[(size_t)g * psize4];
            s0 += u & 255u; s1 += (u >> 8) & 255u;
            s2 += (u >> 16) & 255u; s3 += u >> 24;
        }
        dis[i] = rsqrtf((float)s0 + 1.0f);
        if (i + 1 < n) dis[i + 1] = rsqrtf((float)s1 + 1.0f);
        if (i + 2 < n) dis[i + 2] = rsqrtf((float)s2 + 1.0f);
        if (i + 3 < n) dis[i + 3] = rsqrtf((float)s3 + 1.0f);
    } else {
        int sb = b - ndis4;
        int i = sb * 256 + t;
        int v = M[i];
        sc[t] = v;
        __syncthreads();
        for (int d = 1; d < 256; d <<= 1) {
            int u = (t >= d) ? sc[t - d] : 0;
            __syncthreads(); sc[t] += u; __syncthreads();
        }
        M[i] = sc[t] - v;
        if (t == 255) bsum[sb] = sc[255];
    }
}

// --- dispatch 3: coarse scatter (inline bsum scan) ---
__global__ void k_csc(const int* __restrict__ row, const int* __restrict__ col,
                      const int* __restrict__ M, const int* __restrict__ bsum,
                      int* __restrict__ s4, int E, int CH, int P) {
    __shared__ int sc[256];
    __shared__ int bs[256];
    __shared__ int cur[MAXP];
    int t = threadIdx.x, b = blockIdx.x;
    int v = (t < P) ? bsum[t] : 0;
    sc[t] = v;
    __syncthreads();
    for (int d = 1; d < 256; d <<= 1) {
        int u = (t >= d) ? sc[t - d] : 0;
        __syncthreads(); sc[t] += u; __syncthreads();
    }
    bs[t] = sc[t] - v;
    __syncthreads();
    for (int p = t; p < P; p += 256) cur[p] = bs[p] + M[p * NB + b];
    __syncthreads();
    int s = b * CH, e = min(s + CH, E);
    for (int i = s + t; i < e; i += 256) {
        int r = row[i], c = col[i];
        int pos = atomicAdd(&cur[c >> 9], 1);
        s4[pos] = (r << 9) | (c & 511);
    }
}

// --- dispatch 4: fine sort (blocks < P) ∥ k_linc (blocks >= P) ---
__global__ __launch_bounds__(256, 4)
void k_fl(const int* __restrict__ s4, const int* __restrict__ M,
          const int* __restrict__ bsum, int* __restrict__ rows4,
          int* __restrict__ off,
          const float* __restrict__ x, const float* __restrict__ feat,
          const float* __restrict__ W, const float* __restrict__ bvec,
          const float* __restrict__ dis, bf16* __restrict__ g1,
          int n, int E, int P) {
    __shared__ int sc[256];
    __shared__ int bs[256];
    __shared__ int hist[BW];
    __shared__ int loff[BW];
    __shared__ int tmp[256];
    __shared__ float sIn[4][FDIM];
    int t = threadIdx.x, b = blockIdx.x;
    if (b < P) {
        int v = (t < P) ? bsum[t] : 0;
        sc[t] = v;
        __syncthreads();
        for (int d = 1; d < 256; d <<= 1) {
            int u = (t >= d) ? sc[t - d] : 0;
            __syncthreads(); sc[t] += u; __syncthreads();
        }
        bs[t] = sc[t] - v;
        __syncthreads();
        int gs = bs[b];
        int ge = gs + bsum[b];
        int c0 = b << 9;
        int lim = n - c0; if (lim > BW) lim = BW;
        hist[2 * t] = 0; hist[2 * t + 1] = 0;
        __syncthreads();
        for (int i = gs + t; i < ge; i += 256)
            atomicAdd(&hist[s4[i] & 511], 1);
        __syncthreads();
        int s0 = hist[2 * t], s1v = hist[2 * t + 1];
        int ps = s0 + s1v;
        tmp[t] = ps;
        __syncthreads();
        for (int d = 1; d < 256; d <<= 1) {
            int u = (t >= d) ? tmp[t - d] : 0;
            __syncthreads(); tmp[t] += u; __syncthreads();
        }
        int ex = tmp[t] - ps;
        loff[2 * t] = ex;
        loff[2 * t + 1] = ex + s0;
        __syncthreads();
        for (int i = t; i < lim; i += 256) off[c0 + i] = gs + loff[i];
        if (b == P - 1 && t == 0) off[n] = E;
        __syncthreads();
        for (int i = gs + t; i < ge; i += 256) {
            int v2 = s4[i];
            int pos = gs + atomicAdd(&loff[v2 & 511], 1);
            rows4[pos] = v2 >> 9;
        }
    } else {                                  // k_linc (r9 proven form)
        int local = t >> 6, j = t & 63;
        float Wreg[FDIM];
        #pragma unroll
        for (int k = 0; k < FDIM; ++k) Wreg[k] = W[k * FDIM + j];
        float bj = bvec[j];
        int gw = (b - P) * 4 + local;
        int nwl = GPLIN * 4;
        for (int w = gw; w < n; w += nwl) {
            sIn[local][j] = (j < 32) ? x[(size_t)w * 32 + j]
                                     : feat[(size_t)w * 32 + (j - 32)];
            __threadfence_block();
            float o = bj;
            #pragma unroll
            for (int k4 = 0; k4 < 16; ++k4) {
                float4 h4 = *(const float4*)&sIn[local][k4 * 4];
                o = fmaf(h4.x, Wreg[4 * k4 + 0], o);
                o = fmaf(h4.y, Wreg[4 * k4 + 1], o);
                o = fmaf(h4.z, Wreg[4 * k4 + 2], o);
                o = fmaf(h4.w, Wreg[4 * k4 + 3], o);
            }
            g1[(size_t)w * FDIM + j] = __float2bfloat16(dis[w] * o);
            __threadfence_block();
        }
    }
}

// --- dual-edge gather (v14 proven form, 50.3 us): a[w][j] =
// relu(dis[w]*(g[w][j]+Σ g[r][j])), bf16 out. Wave = 1 node; half-wave h
// carries edge-slot parity, ushort2 per lane = 256 B (2 rows) per
// instruction; 8-deep unroll keeps 8 loads in flight.
__global__ __launch_bounds__(256, 8)
void k_gather(const int* __restrict__ rows4, const int* __restrict__ off,
              const float* __restrict__ dis, const bf16* __restrict__ g,
              bf16* __restrict__ a, int n) {
    int t = blockIdx.x * blockDim.x + threadIdx.x;
    int w = t >> 6;
    if (w >= n) return;
    int lane = threadIdx.x & 63;
    int h = lane >> 5;          // edge-slot parity
    int j2 = lane & 31;         // feature pair index
    const unsigned* g32 = (const unsigned*)g;   // one row = 32 uints
    float acc0 = 0.0f, acc1 = 0.0f;
    int s = off[w], e = off[w + 1];
    for (int k = s; k < e; k += 16) {
        #pragma unroll
        for (int i = 0; i < 8; ++i) {
            int idx = k + 2 * i + h;
            int r = rows4[min(idx, e - 1)];
            unsigned u = g32[(size_t)r * 32 + j2];
            float wg = (idx < e) ? 1.0f : 0.0f;
            acc0 = fmaf(wg, ulo2f(u), acc0);
            acc1 = fmaf(wg, uhi2f(u), acc1);
        }
    }
    acc0 += __shfl_xor(acc0, 32, 64);
    acc1 += __shfl_xor(acc1, 32, 64);
    if (h == 0) {
        unsigned su = g32[(size_t)w * 32 + j2];    // self loop
        float dv = dis[w];
        float v0 = fmaxf(dv * (acc0 + ulo2f(su)), 0.0f);
        float v1 = fmaxf(dv * (acc1 + uhi2f(su)), 0.0f);
        ((unsigned*)a)[(size_t)w * 32 + j2] = f2bu(v0) | (f2bu(v1) << 16);
    }
}

// --- MFMA matvec: o = A@W + b ; FINAL ? relu(o) f32 : bf16(dis*o) ---
// Layouts (guide-verified): A-frag A[m=lane&15][k=quad*8+j];
// B-frag B[k=quad*8+j][n=lane&15]; C/D: n=lane&15, m=quad*4+reg.
template <bool FINAL>
__global__ __launch_bounds__(256, 4)
void k_mat(const bf16* __restrict__ A, const float* __restrict__ W,
           const float* __restrict__ bvec, const float* __restrict__ dis,
           void* __restrict__ outp, int n) {
    __shared__ __align__(16) bf16 sWt[FDIM * FDIM];   // Wt[n][k] (transposed)
    int t = threadIdx.x;
    for (int idx = t; idx < FDIM * FDIM; idx += 256) {
        int kk = idx >> 6, nn = idx & 63;
        sWt[nn * FDIM + kk] = __float2bfloat16(W[idx]);
    }
    __syncthreads();
    int wave = t >> 6, lane = t & 63;
    int quad = lane >> 4, l15 = lane & 15;
    v8s bfr[4][2];
    #pragma unroll
    for (int nt = 0; nt < 4; ++nt) {
        #pragma unroll
        for (int kf = 0; kf < 2; ++kf)
            bfr[nt][kf] = *(const v8s*)&sWt[(nt * 16 + l15) * FDIM + kf * 32 + quad * 8];
    }
    float bj[4];
    #pragma unroll
    for (int nt = 0; nt < 4; ++nt) bj[nt] = bvec[nt * 16 + l15];

    int ntiles = (n + 15) >> 4;
    int step = gridDim.x * 4;
    for (int tile = blockIdx.x * 4 + wave; tile < ntiles; tile += step) {
        int m0 = tile << 4;
        int mA = m0 + l15; if (mA >= n) mA = n - 1;
        v8s af0 = *(const v8s*)&A[(size_t)mA * FDIM + quad * 8];
        v8s af1 = *(const v8s*)&A[(size_t)mA * FDIM + 32 + quad * 8];
        v4f acc[4];
        #pragma unroll
        for (int nt = 0; nt < 4; ++nt) {
            acc[nt] = (v4f){0.f, 0.f, 0.f, 0.f};
            acc[nt] = __builtin_amdgcn_mfma_f32_16x16x32_bf16(af0, bfr[nt][0], acc[nt], 0, 0, 0);
            acc[nt] = __builtin_amdgcn_mfma_f32_16x16x32_bf16(af1, bfr[nt][1], acc[nt], 0, 0, 0);
        }
        #pragma unroll
        for (int r = 0; r < 4; ++r) {
            int node = m0 + quad * 4 + r;
            if (node >= n) continue;
            float dv = FINAL ? 0.0f : dis[node];
            #pragma unroll
            for (int nt = 0; nt < 4; ++nt) {
                int j = nt * 16 + l15;
                float o = acc[nt][r] + bj[nt];
                if (FINAL) ((float*)outp)[(size_t)node * FDIM + j] = fmaxf(o, 0.0f);
                else ((bf16*)outp)[(size_t)node * FDIM + j] = __float2bfloat16(dv * o);
            }
        }
    }
}

extern "C" void kernel_launch(void* const* d_in, const int* in_sizes, int n_in,
                              void* d_out, int out_size, void* d_ws, size_t ws_size,
                              hipStream_t stream) {
    const float* x    = (const float*)d_in[0];
    const float* feat = (const float*)d_in[1];
    const int*   ei   = (const int*)d_in[2];
    const float* W1   = (const float*)d_in[3];
    const float* b1   = (const float*)d_in[4];
    const float* W2   = (const float*)d_in[5];
    const float* b2   = (const float*)d_in[6];
    const float* Wfc  = (const float*)d_in[7];
    const float* bfc  = (const float*)d_in[8];
    float* out = (float*)d_out;

    const int n = in_sizes[0] / 32;   // 100000
    const int E = in_sizes[2] / 2;    // 1600000
    const int* row = ei;
    const int* col = ei + E;

    // u8 histogram partitioning: psize nodes/partition, multiple of 4
    const int psize = (((n + NPART - 1) / NPART) + 3) & ~3;   // 25000
    const int psize4 = psize >> 2;                            // 6250
    const int P  = (n + BW - 1) / BW;            // 196
    const int CH = (E + NB - 1) / NB;            // 6250
    const int total = P * NB;                    // 50176
    const int ndis4 = (((n + 3) / 4) + 255) / 256;            // 98

    // ws: off[n+1] | dis[n] | M[total] | bsum[256] | s4[E] | rows4[E]
    //     | (16B-aligned) bufA(bf16 64n) | bufB(bf16 64n)
    // part (NPART*GPB*psize4 u32 = 6.4 MB) aliases bufA (consumed in k_ds1
    // before k_fl writes g1 into bufA).
    int*   off  = (int*)d_ws;
    float* dis  = (float*)(off + (size_t)n + 1);
    int*   M    = (int*)(dis + n);
    int*   bsum = M + (size_t)total;
    int*   s4    = bsum + 256;
    int*   rows4 = s4 + E;
    size_t co = (size_t)(rows4 + E - (int*)d_ws);
    co = (co + 3) & ~(size_t)3;                  // 16B align for v8s loads
    bf16*  bufA  = (bf16*)((int*)d_ws + co);
    bf16*  bufB  = bufA + (size_t)n * FDIM;
    unsigned* part = (unsigned*)bufA;

    const int B = 256;

    k_h<<<NPART * GPB + NB, B, 0, stream>>>(row, col, part, M, E, n, psize, psize4, P, CH);
    k_ds1<<<ndis4 + P, B, 0, stream>>>(part, dis, M, bsum, n, psize4, ndis4, P);
    k_csc<<<NB, B, 0, stream>>>(row, col, M, bsum, s4, E, CH, P);
    k_fl<<<P + GPLIN, B, 0, stream>>>(s4, M, bsum, rows4, off,
                                      x, feat, W1, b1, dis, bufA, n, E, P);
    // layer 2: gather(g1)->a1 ; mat: g2 = bf16(dis*(a1@W2+b2))
    k_gather<<<(n + 3) / 4, B, 0, stream>>>(rows4, off, dis, bufA, bufB, n);
    k_mat<false><<<512, B, 0, stream>>>(bufB, W2, b2, dis, bufA, n);
    // fc: gather(g2)->a2 ; out = relu(a2@Wfc+bfc)
    k_gather<<<(n + 3) / 4, B, 0, stream>>>(rows4, off, dis, bufA, bufB, n);
    k_mat<true><<<512, B, 0, stream>>>(bufB, Wfc, bfc, dis, out, n);
}

// Round 7
// 282.578 us; speedup vs baseline: 1.1615x; 1.0163x over previous
//
#include <hip/hip_runtime.h>
#include <hip/hip_bf16.h>

// GCN v17 — v16 base (proven 287 us) + build-phase split & widened blocks.
//   r16 analysis: gather (2x49.7 us) is at 93% of the 3.75 TB/s random-row
//   ceiling — near its wall. Non-gather = 187.8 us across 6 dispatches, yet
//   traffic models predict ~half that: build kernels (col-hist, csc, fine
//   sort) run 196-256 blocks x 4 waves = 1 wave/SIMD — latency-bound
//   load->LDS-atomic chains with no TLP. v17: (a) split fused kernels into
//   k_hd/k_hc/k_ds1/k_csc/k_fsort/k_linc for top-5 attribution; (b) widen
//   k_hc/k_csc/k_fsort to 1024-thread blocks (4x waves/CU, same grids).
//   Scan sections guarded to t<256 with all-thread barriers. Gather & mat
//   byte-identical to v16.

#define FDIM 64
#define NPART 4
#define GPB 64
#define NB 256
#define BW 512
#define MAXP 1024
#define GPLIN 1024

typedef __hip_bfloat16 bf16;
typedef short v8s __attribute__((ext_vector_type(8)));
typedef float v4f __attribute__((ext_vector_type(4)));

static __device__ __forceinline__ float ulo2f(unsigned u) {
    union { unsigned x; float f; } v; v.x = u << 16; return v.f;
}
static __device__ __forceinline__ float uhi2f(unsigned u) {
    union { unsigned x; float f; } v; v.x = u & 0xFFFF0000u; return v.f;
}
static __device__ __forceinline__ unsigned f2bu(float f) {
    bf16 b = __float2bfloat16(f);
    return (unsigned)(*(unsigned short*)&b);
}

// --- deg u8-packed partial histograms: 4 partitions x 64 blocks ---
__global__ __launch_bounds__(1024)
void k_hd(const int* __restrict__ row, unsigned* __restrict__ part,
          int E, int n, int psize, int psize4) {
    __shared__ unsigned sm[6256];
    int t = threadIdx.x, b = blockIdx.x;
    int p = b >> 6, g = b & 63;
    int base = p * psize;
    int lim = n - base; if (lim > psize) lim = psize;
    int lim4 = (lim + 3) >> 2;
    for (int i = t; i < lim4; i += 1024) sm[i] = 0u;
    __syncthreads();
    for (int e = g * 1024 + t; e < E; e += GPB * 1024) {
        int r = row[e] - base;
        if ((unsigned)r < (unsigned)lim)
            atomicAdd(&sm[r >> 2], 1u << ((r & 3) * 8));
    }
    __syncthreads();
    unsigned* dst = part + ((size_t)p * GPB + g) * psize4;
    for (int i = t; i < lim4; i += 1024) dst[i] = sm[i];
}

// --- coarse col histogram: NB blocks x 1024 threads ---
__global__ __launch_bounds__(1024)
void k_hc(const int* __restrict__ col, int* __restrict__ M,
          int E, int P, int CH) {
    __shared__ int h[MAXP];
    int t = threadIdx.x, cb = blockIdx.x;
    for (int i = t; i < P; i += 1024) h[i] = 0;
    __syncthreads();
    int s = cb * CH, e = min(s + CH, E);
    for (int i = s + t; i < e; i += 1024)
        atomicAdd(&h[col[i] >> 9], 1);
    __syncthreads();
    for (int p = t; p < P; p += 1024) M[p * NB + cb] = h[p];
}

// --- dis from u8 partials (4 nodes/thread) ∥ scan pass 1 ---
__global__ void k_ds1(const unsigned* __restrict__ part, float* __restrict__ dis,
                      int* __restrict__ M, int* __restrict__ bsum,
                      int n, int psize4, int ndis4, int P) {
    __shared__ int sc[256];
    int t = threadIdx.x, b = blockIdx.x;
    if (b < ndis4) {
        int i4 = b * 256 + t;
        int i = i4 * 4;
        if (i >= n) return;
        int p = i4 / psize4, loc = i4 - p * psize4;
        const unsigned* src = part + (size_t)p * GPB * psize4 + loc;
        unsigned s0 = 0, s1 = 0, s2 = 0, s3 = 0;
        #pragma unroll 8
        for (int g = 0; g < GPB; ++g) {
            unsigned u = src[(size_t)g * psize4];
            s0 += u & 255u; s1 += (u >> 8) & 255u;
            s2 += (u >> 16) & 255u; s3 += u >> 24;
        }
        dis[i] = rsqrtf((float)s0 + 1.0f);
        if (i + 1 < n) dis[i + 1] = rsqrtf((float)s1 + 1.0f);
        if (i + 2 < n) dis[i + 2] = rsqrtf((float)s2 + 1.0f);
        if (i + 3 < n) dis[i + 3] = rsqrtf((float)s3 + 1.0f);
    } else {
        int sb = b - ndis4;
        int i = sb * 256 + t;
        int v = M[i];
        sc[t] = v;
        __syncthreads();
        for (int d = 1; d < 256; d <<= 1) {
            int u = (t >= d) ? sc[t - d] : 0;
            __syncthreads(); sc[t] += u; __syncthreads();
        }
        M[i] = sc[t] - v;
        if (t == 255) bsum[sb] = sc[255];
    }
}

// --- coarse scatter, 1024 threads (scan guarded to t<256) ---
__global__ __launch_bounds__(1024)
void k_csc(const int* __restrict__ row, const int* __restrict__ col,
           const int* __restrict__ M, const int* __restrict__ bsum,
           int* __restrict__ s4, int E, int CH, int P) {
    __shared__ int sc[256];
    __shared__ int bs[256];
    __shared__ int cur[MAXP];
    int t = threadIdx.x, b = blockIdx.x;
    if (t < 256) { int v = (t < P) ? bsum[t] : 0; sc[t] = v; bs[t] = v; }
    __syncthreads();
    for (int d = 1; d < 256; d <<= 1) {
        int u = (t < 256 && t >= d) ? sc[t - d] : 0;
        __syncthreads();
        if (t < 256) sc[t] += u;
        __syncthreads();
    }
    if (t < 256) bs[t] = sc[t] - bs[t];
    __syncthreads();
    for (int p = t; p < P; p += 1024) cur[p] = bs[p] + M[p * NB + b];
    __syncthreads();
    int s = b * CH, e = min(s + CH, E);
    for (int i = s + t; i < e; i += 1024) {
        int r = row[i], c = col[i];
        int pos = atomicAdd(&cur[c >> 9], 1);
        s4[pos] = (r << 9) | (c & 511);
    }
}

// --- fine counting sort, 1024 threads (scans guarded to t<256) ---
__global__ __launch_bounds__(1024)
void k_fsort(const int* __restrict__ s4, const int* __restrict__ bsum,
             int* __restrict__ rows4, int* __restrict__ off,
             int n, int E, int P) {
    __shared__ int sc[256];
    __shared__ int bs[256];
    __shared__ int hist[BW];
    __shared__ int loff[BW];
    __shared__ int tmp[256];
    int t = threadIdx.x, b = blockIdx.x;
    if (t < 256) { int v = (t < P) ? bsum[t] : 0; sc[t] = v; bs[t] = v; }
    __syncthreads();
    for (int d = 1; d < 256; d <<= 1) {
        int u = (t < 256 && t >= d) ? sc[t - d] : 0;
        __syncthreads();
        if (t < 256) sc[t] += u;
        __syncthreads();
    }
    if (t < 256) bs[t] = sc[t] - bs[t];
    __syncthreads();
    int gs = bs[b];
    int ge = gs + bsum[b];
    int c0 = b << 9;
    int lim = n - c0; if (lim > BW) lim = BW;
    for (int i = t; i < BW; i += 1024) hist[i] = 0;
    __syncthreads();
    for (int i = gs + t; i < ge; i += 1024)
        atomicAdd(&hist[s4[i] & 511], 1);
    __syncthreads();
    int s0 = 0, s1v = 0, ps = 0;
    if (t < 256) {
        s0 = hist[2 * t]; s1v = hist[2 * t + 1];
        ps = s0 + s1v;
        tmp[t] = ps;
    }
    __syncthreads();
    for (int d = 1; d < 256; d <<= 1) {
        int u = (t < 256 && t >= d) ? tmp[t - d] : 0;
        __syncthreads();
        if (t < 256) tmp[t] += u;
        __syncthreads();
    }
    if (t < 256) {
        int ex = tmp[t] - ps;
        loff[2 * t] = ex;
        loff[2 * t + 1] = ex + s0;
    }
    __syncthreads();
    for (int i = t; i < lim; i += 1024) off[c0 + i] = gs + loff[i];
    if (b == P - 1 && t == 0) off[n] = E;
    __syncthreads();
    for (int i = gs + t; i < ge; i += 1024) {
        int v2 = s4[i];
        int pos = gs + atomicAdd(&loff[v2 & 511], 1);
        rows4[pos] = v2 >> 9;
    }
}

// --- linear layer 1: g1 = bf16(dis * (concat(x,feat)@W1 + b1)) ---
__global__ __launch_bounds__(256, 4)
void k_linc(const float* __restrict__ x, const float* __restrict__ feat,
            const float* __restrict__ W, const float* __restrict__ bvec,
            const float* __restrict__ dis, bf16* __restrict__ g1, int n) {
    __shared__ float sIn[4][FDIM];
    int t = threadIdx.x;
    int local = t >> 6, j = t & 63;
    float Wreg[FDIM];
    #pragma unroll
    for (int k = 0; k < FDIM; ++k) Wreg[k] = W[k * FDIM + j];
    float bj = bvec[j];
    int gw = blockIdx.x * 4 + local;
    int nwl = GPLIN * 4;
    for (int w = gw; w < n; w += nwl) {
        sIn[local][j] = (j < 32) ? x[(size_t)w * 32 + j]
                                 : feat[(size_t)w * 32 + (j - 32)];
        __threadfence_block();
        float o = bj;
        #pragma unroll
        for (int k4 = 0; k4 < 16; ++k4) {
            float4 h4 = *(const float4*)&sIn[local][k4 * 4];
            o = fmaf(h4.x, Wreg[4 * k4 + 0], o);
            o = fmaf(h4.y, Wreg[4 * k4 + 1], o);
            o = fmaf(h4.z, Wreg[4 * k4 + 2], o);
            o = fmaf(h4.w, Wreg[4 * k4 + 3], o);
        }
        g1[(size_t)w * FDIM + j] = __float2bfloat16(dis[w] * o);
        __threadfence_block();
    }
}

// --- dual-edge gather (v14 proven form, 49.7 us): a[w][j] =
// relu(dis[w]*(g[w][j]+Σ g[r][j])), bf16 out. Wave = 1 node; half-wave h
// carries edge-slot parity, ushort2 per lane = 256 B (2 rows) per
// instruction; 8-deep unroll keeps 8 loads in flight.
__global__ __launch_bounds__(256, 8)
void k_gather(const int* __restrict__ rows4, const int* __restrict__ off,
              const float* __restrict__ dis, const bf16* __restrict__ g,
              bf16* __restrict__ a, int n) {
    int t = blockIdx.x * blockDim.x + threadIdx.x;
    int w = t >> 6;
    if (w >= n) return;
    int lane = threadIdx.x & 63;
    int h = lane >> 5;          // edge-slot parity
    int j2 = lane & 31;         // feature pair index
    const unsigned* g32 = (const unsigned*)g;   // one row = 32 uints
    float acc0 = 0.0f, acc1 = 0.0f;
    int s = off[w], e = off[w + 1];
    for (int k = s; k < e; k += 16) {
        #pragma unroll
        for (int i = 0; i < 8; ++i) {
            int idx = k + 2 * i + h;
            int r = rows4[min(idx, e - 1)];
            unsigned u = g32[(size_t)r * 32 + j2];
            float wg = (idx < e) ? 1.0f : 0.0f;
            acc0 = fmaf(wg, ulo2f(u), acc0);
            acc1 = fmaf(wg, uhi2f(u), acc1);
        }
    }
    acc0 += __shfl_xor(acc0, 32, 64);
    acc1 += __shfl_xor(acc1, 32, 64);
    if (h == 0) {
        unsigned su = g32[(size_t)w * 32 + j2];    // self loop
        float dv = dis[w];
        float v0 = fmaxf(dv * (acc0 + ulo2f(su)), 0.0f);
        float v1 = fmaxf(dv * (acc1 + uhi2f(su)), 0.0f);
        ((unsigned*)a)[(size_t)w * 32 + j2] = f2bu(v0) | (f2bu(v1) << 16);
    }
}

// --- MFMA matvec: o = A@W + b ; FINAL ? relu(o) f32 : bf16(dis*o) ---
// Layouts (guide-verified): A-frag A[m=lane&15][k=quad*8+j];
// B-frag B[k=quad*8+j][n=lane&15]; C/D: n=lane&15, m=quad*4+reg.
template <bool FINAL>
__global__ __launch_bounds__(256, 4)
void k_mat(const bf16* __restrict__ A, const float* __restrict__ W,
           const float* __restrict__ bvec, const float* __restrict__ dis,
           void* __restrict__ outp, int n) {
    __shared__ __align__(16) bf16 sWt[FDIM * FDIM];   // Wt[n][k] (transposed)
    int t = threadIdx.x;
    for (int idx = t; idx < FDIM * FDIM; idx += 256) {
        int kk = idx >> 6, nn = idx & 63;
        sWt[nn * FDIM + kk] = __float2bfloat16(W[idx]);
    }
    __syncthreads();
    int wave = t >> 6, lane = t & 63;
    int quad = lane >> 4, l15 = lane & 15;
    v8s bfr[4][2];
    #pragma unroll
    for (int nt = 0; nt < 4; ++nt) {
        #pragma unroll
        for (int kf = 0; kf < 2; ++kf)
            bfr[nt][kf] = *(const v8s*)&sWt[(nt * 16 + l15) * FDIM + kf * 32 + quad * 8];
    }
    float bj[4];
    #pragma unroll
    for (int nt = 0; nt < 4; ++nt) bj[nt] = bvec[nt * 16 + l15];

    int ntiles = (n + 15) >> 4;
    int step = gridDim.x * 4;
    for (int tile = blockIdx.x * 4 + wave; tile < ntiles; tile += step) {
        int m0 = tile << 4;
        int mA = m0 + l15; if (mA >= n) mA = n - 1;
        v8s af0 = *(const v8s*)&A[(size_t)mA * FDIM + quad * 8];
        v8s af1 = *(const v8s*)&A[(size_t)mA * FDIM + 32 + quad * 8];
        v4f acc[4];
        #pragma unroll
        for (int nt = 0; nt < 4; ++nt) {
            acc[nt] = (v4f){0.f, 0.f, 0.f, 0.f};
            acc[nt] = __builtin_amdgcn_mfma_f32_16x16x32_bf16(af0, bfr[nt][0], acc[nt], 0, 0, 0);
            acc[nt] = __builtin_amdgcn_mfma_f32_16x16x32_bf16(af1, bfr[nt][1], acc[nt], 0, 0, 0);
        }
        #pragma unroll
        for (int r = 0; r < 4; ++r) {
            int node = m0 + quad * 4 + r;
            if (node >= n) continue;
            float dv = FINAL ? 0.0f : dis[node];
            #pragma unroll
            for (int nt = 0; nt < 4; ++nt) {
                int j = nt * 16 + l15;
                float o = acc[nt][r] + bj[nt];
                if (FINAL) ((float*)outp)[(size_t)node * FDIM + j] = fmaxf(o, 0.0f);
                else ((bf16*)outp)[(size_t)node * FDIM + j] = __float2bfloat16(dv * o);
            }
        }
    }
}

extern "C" void kernel_launch(void* const* d_in, const int* in_sizes, int n_in,
                              void* d_out, int out_size, void* d_ws, size_t ws_size,
                              hipStream_t stream) {
    const float* x    = (const float*)d_in[0];
    const float* feat = (const float*)d_in[1];
    const int*   ei   = (const int*)d_in[2];
    const float* W1   = (const float*)d_in[3];
    const float* b1   = (const float*)d_in[4];
    const float* W2   = (const float*)d_in[5];
    const float* b2   = (const float*)d_in[6];
    const float* Wfc  = (const float*)d_in[7];
    const float* bfc  = (const float*)d_in[8];
    float* out = (float*)d_out;

    const int n = in_sizes[0] / 32;   // 100000
    const int E = in_sizes[2] / 2;    // 1600000
    const int* row = ei;
    const int* col = ei + E;

    const int psize = (((n + NPART - 1) / NPART) + 3) & ~3;   // 25000
    const int psize4 = psize >> 2;                            // 6250
    const int P  = (n + BW - 1) / BW;            // 196
    const int CH = (E + NB - 1) / NB;            // 6250
    const int total = P * NB;                    // 50176
    const int ndis4 = (((n + 3) / 4) + 255) / 256;            // 98

    // ws: off[n+1] | dis[n] | M[total] | bsum[256] | s4[E] | rows4[E]
    //     | (16B-aligned) bufA(bf16 64n) | bufB(bf16 64n)
    // part (NPART*GPB*psize4 u32 = 6.4 MB) aliases bufA (consumed in k_ds1
    // before k_linc writes g1 into bufA).
    int*   off  = (int*)d_ws;
    float* dis  = (float*)(off + (size_t)n + 1);
    int*   M    = (int*)(dis + n);
    int*   bsum = M + (size_t)total;
    int*   s4    = bsum + 256;
    int*   rows4 = s4 + E;
    size_t co = (size_t)(rows4 + E - (int*)d_ws);
    co = (co + 3) & ~(size_t)3;                  // 16B align for v8s loads
    bf16*  bufA  = (bf16*)((int*)d_ws + co);
    bf16*  bufB  = bufA + (size_t)n * FDIM;
    unsigned* part = (unsigned*)bufA;

    k_hd<<<NPART * GPB, 1024, 0, stream>>>(row, part, E, n, psize, psize4);
    k_hc<<<NB, 1024, 0, stream>>>(col, M, E, P, CH);
    k_ds1<<<ndis4 + P, 256, 0, stream>>>(part, dis, M, bsum, n, psize4, ndis4, P);
    k_csc<<<NB, 1024, 0, stream>>>(row, col, M, bsum, s4, E, CH, P);
    k_fsort<<<P, 1024, 0, stream>>>(s4, bsum, rows4, off, n, E, P);
    k_linc<<<GPLIN, 256, 0, stream>>>(x, feat, W1, b1, dis, bufA, n);
    // layer 2: gather(g1)->a1 ; mat: g2 = bf16(dis*(a1@W2+b2))
    k_gather<<<(n + 3) / 4, 256, 0, stream>>>(rows4, off, dis, bufA, bufB, n);
    k_mat<false><<<512, 256, 0, stream>>>(bufB, W2, b2, dis, bufA, n);
    // fc: gather(g2)->a2 ; out = relu(a2@Wfc+bfc)
    k_gather<<<(n + 3) / 4, 256, 0, stream>>>(rows4, off, dis, bufA, bufB, n);
    k_mat<true><<<512, 256, 0, stream>>>(bufB, Wfc, bfc, dis, out, n);
}

// Round 8
// 274.707 us; speedup vs baseline: 1.1947x; 1.0287x over previous
//
#include <hip/hip_runtime.h>
#include <hip/hip_bf16.h>

// GCN v18 — v17 base (proven 282.6 us) + int4 edge sweeps + gather tail-split.
//   r17 analysis: all build kernels < 49.7 us (top-5 cutoff); v14 evidence
//   (k_h: 636 GB/s, VALU 5.4%, FETCH 6.3 MB) says edge-sweep kernels are
//   load-LATENCY-chain bound (L3 absorbs re-reads). v18: int4 loads in
//   k_hd/k_hc/k_csc -> 4 edges per chain, 4x MLP at same occupancy; CH
//   rounded to x4 for 16B alignment. Gather: re-apply v15 tail-split
//   (49.7 vs 50.2 measured). Slab-gather re-rejected by arithmetic:
//   4-pass VALU x2.6 on a 56%-VALU kernel becomes the wall.

#define FDIM 64
#define NPART 4
#define GPB 64
#define NB 256
#define BW 512
#define MAXP 1024
#define GPLIN 1024

typedef __hip_bfloat16 bf16;
typedef short v8s __attribute__((ext_vector_type(8)));
typedef float v4f __attribute__((ext_vector_type(4)));

static __device__ __forceinline__ float ulo2f(unsigned u) {
    union { unsigned x; float f; } v; v.x = u << 16; return v.f;
}
static __device__ __forceinline__ float uhi2f(unsigned u) {
    union { unsigned x; float f; } v; v.x = u & 0xFFFF0000u; return v.f;
}
static __device__ __forceinline__ unsigned f2bu(float f) {
    bf16 b = __float2bfloat16(f);
    return (unsigned)(*(unsigned short*)&b);
}

// --- deg u8-packed partial histograms: 4 partitions x 64 blocks, int4 sweep ---
__global__ __launch_bounds__(1024)
void k_hd(const int* __restrict__ row, unsigned* __restrict__ part,
          int E, int n, int psize, int psize4) {
    __shared__ unsigned sm[6256];
    int t = threadIdx.x, b = blockIdx.x;
    int p = b >> 6, g = b & 63;
    int base = p * psize;
    int lim = n - base; if (lim > psize) lim = psize;
    int lim4 = (lim + 3) >> 2;
    for (int i = t; i < lim4; i += 1024) sm[i] = 0u;
    __syncthreads();
    // E % 4 == 0: every int4 batch is fully in-bounds and 16B-aligned.
    for (int e = (g * 1024 + t) * 4; e < E; e += GPB * 4096) {
        int4 r4 = *(const int4*)&row[e];
        int r0 = r4.x - base, r1 = r4.y - base, r2 = r4.z - base, r3 = r4.w - base;
        if ((unsigned)r0 < (unsigned)lim) atomicAdd(&sm[r0 >> 2], 1u << ((r0 & 3) * 8));
        if ((unsigned)r1 < (unsigned)lim) atomicAdd(&sm[r1 >> 2], 1u << ((r1 & 3) * 8));
        if ((unsigned)r2 < (unsigned)lim) atomicAdd(&sm[r2 >> 2], 1u << ((r2 & 3) * 8));
        if ((unsigned)r3 < (unsigned)lim) atomicAdd(&sm[r3 >> 2], 1u << ((r3 & 3) * 8));
    }
    __syncthreads();
    unsigned* dst = part + ((size_t)p * GPB + g) * psize4;
    for (int i = t; i < lim4; i += 1024) dst[i] = sm[i];
}

// --- coarse col histogram: NB blocks x 1024 threads, int4 sweep ---
__global__ __launch_bounds__(1024)
void k_hc(const int* __restrict__ col, int* __restrict__ M,
          int E, int P, int CH) {
    __shared__ int h[MAXP];
    int t = threadIdx.x, cb = blockIdx.x;
    for (int i = t; i < P; i += 1024) h[i] = 0;
    __syncthreads();
    int s = cb * CH, e = min(s + CH, E);   // s, e multiples of 4 (CH % 4 == 0)
    for (int i = s + t * 4; i < e; i += 4096) {
        int4 c4 = *(const int4*)&col[i];
        atomicAdd(&h[c4.x >> 9], 1);
        atomicAdd(&h[c4.y >> 9], 1);
        atomicAdd(&h[c4.z >> 9], 1);
        atomicAdd(&h[c4.w >> 9], 1);
    }
    __syncthreads();
    for (int p = t; p < P; p += 1024) M[p * NB + cb] = h[p];
}

// --- dis from u8 partials (4 nodes/thread) ∥ scan pass 1 ---
__global__ void k_ds1(const unsigned* __restrict__ part, float* __restrict__ dis,
                      int* __restrict__ M, int* __restrict__ bsum,
                      int n, int psize4, int ndis4, int P) {
    __shared__ int sc[256];
    int t = threadIdx.x, b = blockIdx.x;
    if (b < ndis4) {
        int i4 = b * 256 + t;
        int i = i4 * 4;
        if (i >= n) return;
        int p = i4 / psize4, loc = i4 - p * psize4;
        const unsigned* src = part + (size_t)p * GPB * psize4 + loc;
        unsigned s0 = 0, s1 = 0, s2 = 0, s3 = 0;
        #pragma unroll 8
        for (int g = 0; g < GPB; ++g) {
            unsigned u = src[(size_t)g * psize4];
            s0 += u & 255u; s1 += (u >> 8) & 255u;
            s2 += (u >> 16) & 255u; s3 += u >> 24;
        }
        dis[i] = rsqrtf((float)s0 + 1.0f);
        if (i + 1 < n) dis[i + 1] = rsqrtf((float)s1 + 1.0f);
        if (i + 2 < n) dis[i + 2] = rsqrtf((float)s2 + 1.0f);
        if (i + 3 < n) dis[i + 3] = rsqrtf((float)s3 + 1.0f);
    } else {
        int sb = b - ndis4;
        int i = sb * 256 + t;
        int v = M[i];
        sc[t] = v;
        __syncthreads();
        for (int d = 1; d < 256; d <<= 1) {
            int u = (t >= d) ? sc[t - d] : 0;
            __syncthreads(); sc[t] += u; __syncthreads();
        }
        M[i] = sc[t] - v;
        if (t == 255) bsum[sb] = sc[255];
    }
}

// --- coarse scatter, 1024 threads, int4 sweep (scan guarded to t<256) ---
__global__ __launch_bounds__(1024)
void k_csc(const int* __restrict__ row, const int* __restrict__ col,
           const int* __restrict__ M, const int* __restrict__ bsum,
           int* __restrict__ s4, int E, int CH, int P) {
    __shared__ int sc[256];
    __shared__ int bs[256];
    __shared__ int cur[MAXP];
    int t = threadIdx.x, b = blockIdx.x;
    if (t < 256) { int v = (t < P) ? bsum[t] : 0; sc[t] = v; bs[t] = v; }
    __syncthreads();
    for (int d = 1; d < 256; d <<= 1) {
        int u = (t < 256 && t >= d) ? sc[t - d] : 0;
        __syncthreads();
        if (t < 256) sc[t] += u;
        __syncthreads();
    }
    if (t < 256) bs[t] = sc[t] - bs[t];
    __syncthreads();
    for (int p = t; p < P; p += 1024) cur[p] = bs[p] + M[p * NB + b];
    __syncthreads();
    int s = b * CH, e = min(s + CH, E);   // multiples of 4
    for (int i = s + t * 4; i < e; i += 4096) {
        int4 r4 = *(const int4*)&row[i];
        int4 c4 = *(const int4*)&col[i];
        int p0 = atomicAdd(&cur[c4.x >> 9], 1);
        s4[p0] = (r4.x << 9) | (c4.x & 511);
        int p1 = atomicAdd(&cur[c4.y >> 9], 1);
        s4[p1] = (r4.y << 9) | (c4.y & 511);
        int p2 = atomicAdd(&cur[c4.z >> 9], 1);
        s4[p2] = (r4.z << 9) | (c4.z & 511);
        int p3 = atomicAdd(&cur[c4.w >> 9], 1);
        s4[p3] = (r4.w << 9) | (c4.w & 511);
    }
}

// --- fine counting sort, 1024 threads (scans guarded to t<256) ---
__global__ __launch_bounds__(1024)
void k_fsort(const int* __restrict__ s4, const int* __restrict__ bsum,
             int* __restrict__ rows4, int* __restrict__ off,
             int n, int E, int P) {
    __shared__ int sc[256];
    __shared__ int bs[256];
    __shared__ int hist[BW];
    __shared__ int loff[BW];
    __shared__ int tmp[256];
    int t = threadIdx.x, b = blockIdx.x;
    if (t < 256) { int v = (t < P) ? bsum[t] : 0; sc[t] = v; bs[t] = v; }
    __syncthreads();
    for (int d = 1; d < 256; d <<= 1) {
        int u = (t < 256 && t >= d) ? sc[t - d] : 0;
        __syncthreads();
        if (t < 256) sc[t] += u;
        __syncthreads();
    }
    if (t < 256) bs[t] = sc[t] - bs[t];
    __syncthreads();
    int gs = bs[b];
    int ge = gs + bsum[b];
    int c0 = b << 9;
    int lim = n - c0; if (lim > BW) lim = BW;
    for (int i = t; i < BW; i += 1024) hist[i] = 0;
    __syncthreads();
    for (int i = gs + t; i < ge; i += 1024)
        atomicAdd(&hist[s4[i] & 511], 1);
    __syncthreads();
    int s0 = 0, s1v = 0, ps = 0;
    if (t < 256) {
        s0 = hist[2 * t]; s1v = hist[2 * t + 1];
        ps = s0 + s1v;
        tmp[t] = ps;
    }
    __syncthreads();
    for (int d = 1; d < 256; d <<= 1) {
        int u = (t < 256 && t >= d) ? tmp[t - d] : 0;
        __syncthreads();
        if (t < 256) tmp[t] += u;
        __syncthreads();
    }
    if (t < 256) {
        int ex = tmp[t] - ps;
        loff[2 * t] = ex;
        loff[2 * t + 1] = ex + s0;
    }
    __syncthreads();
    for (int i = t; i < lim; i += 1024) off[c0 + i] = gs + loff[i];
    if (b == P - 1 && t == 0) off[n] = E;
    __syncthreads();
    for (int i = gs + t; i < ge; i += 1024) {
        int v2 = s4[i];
        int pos = gs + atomicAdd(&loff[v2 & 511], 1);
        rows4[pos] = v2 >> 9;
    }
}

// --- linear layer 1: g1 = bf16(dis * (concat(x,feat)@W1 + b1)) ---
__global__ __launch_bounds__(256, 4)
void k_linc(const float* __restrict__ x, const float* __restrict__ feat,
            const float* __restrict__ W, const float* __restrict__ bvec,
            const float* __restrict__ dis, bf16* __restrict__ g1, int n) {
    __shared__ float sIn[4][FDIM];
    int t = threadIdx.x;
    int local = t >> 6, j = t & 63;
    float Wreg[FDIM];
    #pragma unroll
    for (int k = 0; k < FDIM; ++k) Wreg[k] = W[k * FDIM + j];
    float bj = bvec[j];
    int gw = blockIdx.x * 4 + local;
    int nwl = GPLIN * 4;
    for (int w = gw; w < n; w += nwl) {
        sIn[local][j] = (j < 32) ? x[(size_t)w * 32 + j]
                                 : feat[(size_t)w * 32 + (j - 32)];
        __threadfence_block();
        float o = bj;
        #pragma unroll
        for (int k4 = 0; k4 < 16; ++k4) {
            float4 h4 = *(const float4*)&sIn[local][k4 * 4];
            o = fmaf(h4.x, Wreg[4 * k4 + 0], o);
            o = fmaf(h4.y, Wreg[4 * k4 + 1], o);
            o = fmaf(h4.z, Wreg[4 * k4 + 2], o);
            o = fmaf(h4.w, Wreg[4 * k4 + 3], o);
        }
        g1[(size_t)w * FDIM + j] = __float2bfloat16(dis[w] * o);
        __threadfence_block();
    }
}

// --- dual-edge gather + tail-split: a[w][j] = relu(dis[w]*(g[w][j]+Σ g[r][j])).
// Wave = 1 node; half-wave h carries edge-slot parity, ushort2 per lane =
// 256 B (2 rows) per instruction; 8-deep unroll keeps 8 loads in flight.
// Full 16-edge chunks run clamp-free; single masked tail chunk.
__global__ __launch_bounds__(256, 8)
void k_gather(const int* __restrict__ rows4, const int* __restrict__ off,
              const float* __restrict__ dis, const bf16* __restrict__ g,
              bf16* __restrict__ a, int n) {
    int t = blockIdx.x * blockDim.x + threadIdx.x;
    int w = t >> 6;
    if (w >= n) return;
    int lane = threadIdx.x & 63;
    int h = lane >> 5;          // edge-slot parity
    int j2 = lane & 31;         // feature pair index
    const unsigned* g32 = (const unsigned*)g;   // one row = 32 uints
    float acc0 = 0.0f, acc1 = 0.0f;
    int s = off[w], e = off[w + 1];
    int k = s;
    for (; k + 16 <= e; k += 16) {
        #pragma unroll
        for (int i = 0; i < 8; ++i) {
            int r = rows4[k + 2 * i + h];
            unsigned u = g32[(size_t)r * 32 + j2];
            acc0 += ulo2f(u);
            acc1 += uhi2f(u);
        }
    }
    if (k < e) {
        #pragma unroll
        for (int i = 0; i < 8; ++i) {
            int idx = k + 2 * i + h;
            int r = rows4[min(idx, e - 1)];
            unsigned u = g32[(size_t)r * 32 + j2];
            float wg = (idx < e) ? 1.0f : 0.0f;
            acc0 = fmaf(wg, ulo2f(u), acc0);
            acc1 = fmaf(wg, uhi2f(u), acc1);
        }
    }
    acc0 += __shfl_xor(acc0, 32, 64);
    acc1 += __shfl_xor(acc1, 32, 64);
    if (h == 0) {
        unsigned su = g32[(size_t)w * 32 + j2];    // self loop
        float dv = dis[w];
        float v0 = fmaxf(dv * (acc0 + ulo2f(su)), 0.0f);
        float v1 = fmaxf(dv * (acc1 + uhi2f(su)), 0.0f);
        ((unsigned*)a)[(size_t)w * 32 + j2] = f2bu(v0) | (f2bu(v1) << 16);
    }
}

// --- MFMA matvec: o = A@W + b ; FINAL ? relu(o) f32 : bf16(dis*o) ---
// Layouts (guide-verified): A-frag A[m=lane&15][k=quad*8+j];
// B-frag B[k=quad*8+j][n=lane&15]; C/D: n=lane&15, m=quad*4+reg.
template <bool FINAL>
__global__ __launch_bounds__(256, 4)
void k_mat(const bf16* __restrict__ A, const float* __restrict__ W,
           const float* __restrict__ bvec, const float* __restrict__ dis,
           void* __restrict__ outp, int n) {
    __shared__ __align__(16) bf16 sWt[FDIM * FDIM];   // Wt[n][k] (transposed)
    int t = threadIdx.x;
    for (int idx = t; idx < FDIM * FDIM; idx += 256) {
        int kk = idx >> 6, nn = idx & 63;
        sWt[nn * FDIM + kk] = __float2bfloat16(W[idx]);
    }
    __syncthreads();
    int wave = t >> 6, lane = t & 63;
    int quad = lane >> 4, l15 = lane & 15;
    v8s bfr[4][2];
    #pragma unroll
    for (int nt = 0; nt < 4; ++nt) {
        #pragma unroll
        for (int kf = 0; kf < 2; ++kf)
            bfr[nt][kf] = *(const v8s*)&sWt[(nt * 16 + l15) * FDIM + kf * 32 + quad * 8];
    }
    float bj[4];
    #pragma unroll
    for (int nt = 0; nt < 4; ++nt) bj[nt] = bvec[nt * 16 + l15];

    int ntiles = (n + 15) >> 4;
    int step = gridDim.x * 4;
    for (int tile = blockIdx.x * 4 + wave; tile < ntiles; tile += step) {
        int m0 = tile << 4;
        int mA = m0 + l15; if (mA >= n) mA = n - 1;
        v8s af0 = *(const v8s*)&A[(size_t)mA * FDIM + quad * 8];
        v8s af1 = *(const v8s*)&A[(size_t)mA * FDIM + 32 + quad * 8];
        v4f acc[4];
        #pragma unroll
        for (int nt = 0; nt < 4; ++nt) {
            acc[nt] = (v4f){0.f, 0.f, 0.f, 0.f};
            acc[nt] = __builtin_amdgcn_mfma_f32_16x16x32_bf16(af0, bfr[nt][0], acc[nt], 0, 0, 0);
            acc[nt] = __builtin_amdgcn_mfma_f32_16x16x32_bf16(af1, bfr[nt][1], acc[nt], 0, 0, 0);
        }
        #pragma unroll
        for (int r = 0; r < 4; ++r) {
            int node = m0 + quad * 4 + r;
            if (node >= n) continue;
            float dv = FINAL ? 0.0f : dis[node];
            #pragma unroll
            for (int nt = 0; nt < 4; ++nt) {
                int j = nt * 16 + l15;
                float o = acc[nt][r] + bj[nt];
                if (FINAL) ((float*)outp)[(size_t)node * FDIM + j] = fmaxf(o, 0.0f);
                else ((bf16*)outp)[(size_t)node * FDIM + j] = __float2bfloat16(dv * o);
            }
        }
    }
}

extern "C" void kernel_launch(void* const* d_in, const int* in_sizes, int n_in,
                              void* d_out, int out_size, void* d_ws, size_t ws_size,
                              hipStream_t stream) {
    const float* x    = (const float*)d_in[0];
    const float* feat = (const float*)d_in[1];
    const int*   ei   = (const int*)d_in[2];
    const float* W1   = (const float*)d_in[3];
    const float* b1   = (const float*)d_in[4];
    const float* W2   = (const float*)d_in[5];
    const float* b2   = (const float*)d_in[6];
    const float* Wfc  = (const float*)d_in[7];
    const float* bfc  = (const float*)d_in[8];
    float* out = (float*)d_out;

    const int n = in_sizes[0] / 32;   // 100000
    const int E = in_sizes[2] / 2;    // 1600000 (multiple of 4)
    const int* row = ei;
    const int* col = ei + E;

    const int psize = (((n + NPART - 1) / NPART) + 3) & ~3;   // 25000
    const int psize4 = psize >> 2;                            // 6250
    const int P  = (n + BW - 1) / BW;                         // 196
    const int CH = (((E + NB - 1) / NB) + 3) & ~3;            // 6252 (x4 aligned)
    const int total = P * NB;                                 // 50176
    const int ndis4 = (((n + 3) / 4) + 255) / 256;            // 98

    // ws: off[n+1] | dis[n] | M[total] | bsum[256] | s4[E] | rows4[E]
    //     | (16B-aligned) bufA(bf16 64n) | bufB(bf16 64n)
    // part (NPART*GPB*psize4 u32 = 6.4 MB) aliases bufA (consumed in k_ds1
    // before k_linc writes g1 into bufA).
    int*   off  = (int*)d_ws;
    float* dis  = (float*)(off + (size_t)n + 1);
    int*   M    = (int*)(dis + n);
    int*   bsum = M + (size_t)total;
    int*   s4    = bsum + 256;
    int*   rows4 = s4 + E;
    size_t co = (size_t)(rows4 + E - (int*)d_ws);
    co = (co + 3) & ~(size_t)3;                  // 16B align for v8s loads
    bf16*  bufA  = (bf16*)((int*)d_ws + co);
    bf16*  bufB  = bufA + (size_t)n * FDIM;
    unsigned* part = (unsigned*)bufA;

    k_hd<<<NPART * GPB, 1024, 0, stream>>>(row, part, E, n, psize, psize4);
    k_hc<<<NB, 1024, 0, stream>>>(col, M, E, P, CH);
    k_ds1<<<ndis4 + P, 256, 0, stream>>>(part, dis, M, bsum, n, psize4, ndis4, P);
    k_csc<<<NB, 1024, 0, stream>>>(row, col, M, bsum, s4, E, CH, P);
    k_fsort<<<P, 1024, 0, stream>>>(s4, bsum, rows4, off, n, E, P);
    k_linc<<<GPLIN, 256, 0, stream>>>(x, feat, W1, b1, dis, bufA, n);
    // layer 2: gather(g1)->a1 ; mat: g2 = bf16(dis*(a1@W2+b2))
    k_gather<<<(n + 3) / 4, 256, 0, stream>>>(rows4, off, dis, bufA, bufB, n);
    k_mat<false><<<512, 256, 0, stream>>>(bufB, W2, b2, dis, bufA, n);
    // fc: gather(g2)->a2 ; out = relu(a2@Wfc+bfc)
    k_gather<<<(n + 3) / 4, 256, 0, stream>>>(rows4, off, dis, bufA, bufB, n);
    k_mat<true><<<512, 256, 0, stream>>>(bufB, Wfc, bfc, dis, out, n);
}